// Round 1
// baseline (1501.822 us; speedup 1.0000x reference)
//
#include <hip/hip_runtime.h>
#include <hip/hip_bf16.h>
#include <math.h>

#define SEQ  1024
#define BATCH 1024
#define IN_F 57
#define H_F  128
#define OUT_F 18

// Each block: 256 threads = 4 waves, handles 2 batch rows for all SEQ steps.
// thread -> j = tid & 127 (output neuron), bp = tid >> 7 (which of 2 batch rows).
// W_hh row j (128 f32) + W_ih row j (57 f32) live in registers for the whole
// sequence. h state in LDS (double-buffered -> single barrier per step).
// __launch_bounds__(256,2): 2 waves/SIMD (2 blocks/CU), VGPR cap 256.
__global__ __launch_bounds__(256, 2) void rnn_persistent_kernel(
    const float* __restrict__ X,     // [SEQ][BATCH][IN_F]
    const float* __restrict__ W_ih,  // [H_F][IN_F]
    const float* __restrict__ b_ih,  // [H_F]
    const float* __restrict__ W_hh,  // [H_F][H_F]
    const float* __restrict__ b_hh,  // [H_F]
    const float* __restrict__ W_ho,  // [OUT_F][H_F]
    const float* __restrict__ b_ho,  // [OUT_F]
    float* __restrict__ out)         // [BATCH][OUT_F] ++ [BATCH][H_F]
{
    const int tid = threadIdx.x;
    const int j  = tid & (H_F - 1);
    const int bp = tid >> 7;             // 0 or 1
    const int b0 = blockIdx.x * 2;       // first batch row of this block

    __shared__ float h_lds[2][2][H_F];       // [buf][bp][j]
    __shared__ float x_lds[2][2][60];        // [buf][bp][i], padded 57->60 for f4 align
    __shared__ float logits_lds[2][OUT_F];
    __shared__ float red_lds[2][2];          // per-row {max, log(sumexp)}

    // ---- load weights into registers (one-time; L2-served) ----
    float whh[H_F];
    #pragma unroll
    for (int k = 0; k < H_F; ++k) whh[k] = W_hh[j * H_F + k];
    float wih[IN_F];
    #pragma unroll
    for (int i = 0; i < IN_F; ++i) wih[i] = W_ih[j * IN_F + i];
    const float bias = b_ih[j] + b_hh[j];

    // ---- init h0 = 0 and stage x_0 ----
    h_lds[0][bp][j] = 0.0f;
    if (tid < 2 * IN_F) {
        int r = (tid >= IN_F) ? 1 : 0;
        int c = tid - r * IN_F;
        // rows b0, b0+1 are contiguous in X for fixed t
        x_lds[0][r][c] = X[(size_t)b0 * IN_F + tid];
    }
    __syncthreads();

    const size_t stepstride = (size_t)BATCH * IN_F;

    for (int t = 0; t < SEQ; ++t) {
        const int cb = t & 1;
        const int nb = cb ^ 1;

        // prefetch x_{t+1} into a register (stays in flight under the compute)
        float xpre = 0.0f;
        const bool do_pre = (t + 1 < SEQ) && (tid < 2 * IN_F);
        if (do_pre)
            xpre = X[(size_t)(t + 1) * stepstride + (size_t)b0 * IN_F + tid];

        // ---- h2h: 128 MACs, weights in regs, h broadcast from LDS ----
        float a0 = bias, a1 = 0.0f, a2 = 0.0f, a3 = 0.0f;
        const float4* hv = (const float4*)(&h_lds[cb][bp][0]);
        #pragma unroll
        for (int k4 = 0; k4 < H_F / 4; ++k4) {
            float4 hh = hv[k4];
            a0 = fmaf(whh[4 * k4 + 0], hh.x, a0);
            a1 = fmaf(whh[4 * k4 + 1], hh.y, a1);
            a2 = fmaf(whh[4 * k4 + 2], hh.z, a2);
            a3 = fmaf(whh[4 * k4 + 3], hh.w, a3);
        }
        // ---- i2h: 57 MACs ----
        const float4* xv = (const float4*)(&x_lds[cb][bp][0]);
        #pragma unroll
        for (int i4 = 0; i4 < 14; ++i4) {
            float4 xx = xv[i4];
            a0 = fmaf(wih[4 * i4 + 0], xx.x, a0);
            a1 = fmaf(wih[4 * i4 + 1], xx.y, a1);
            a2 = fmaf(wih[4 * i4 + 2], xx.z, a2);
            a3 = fmaf(wih[4 * i4 + 3], xx.w, a3);
        }
        a0 = fmaf(wih[56], x_lds[cb][bp][56], a0);

        const float hnew = tanhf((a0 + a1) + (a2 + a3));

        // write next-state buffers (nobody reads nb this step)
        h_lds[nb][bp][j] = hnew;
        if (do_pre) {
            int r = (tid >= IN_F) ? 1 : 0;
            int c = tid - r * IN_F;
            x_lds[nb][r][c] = xpre;
        }
        __syncthreads();   // single barrier per step
    }

    // final h is in buffer (SEQ & 1) == 0
    // ---- write hT ----
    float* hT = out + (size_t)BATCH * OUT_F;
    hT[(size_t)(b0 + bp) * H_F + j] = h_lds[0][bp][j];

    // ---- logits: [2][18], threads 0..35 ----
    if (tid < 2 * OUT_F) {
        int bb = tid / OUT_F;
        int o  = tid - bb * OUT_F;
        float acc = b_ho[o];
        #pragma unroll
        for (int k = 0; k < H_F; ++k)
            acc = fmaf(h_lds[0][bb][k], W_ho[o * H_F + k], acc);
        logits_lds[bb][o] = acc;
    }
    __syncthreads();

    // ---- per-row max + log-sum-exp ----
    if (tid < 2) {
        float m = -INFINITY;
        #pragma unroll
        for (int o = 0; o < OUT_F; ++o) m = fmaxf(m, logits_lds[tid][o]);
        float s = 0.0f;
        #pragma unroll
        for (int o = 0; o < OUT_F; ++o) s += expf(logits_lds[tid][o] - m);
        red_lds[tid][0] = m;
        red_lds[tid][1] = logf(s);
    }
    __syncthreads();

    // ---- log_softmax write ----
    if (tid < 2 * OUT_F) {
        int bb = tid / OUT_F;
        int o  = tid - bb * OUT_F;
        out[(size_t)(b0 + bb) * OUT_F + o] =
            logits_lds[bb][o] - red_lds[bb][0] - red_lds[bb][1];
    }
}

extern "C" void kernel_launch(void* const* d_in, const int* in_sizes, int n_in,
                              void* d_out, int out_size, void* d_ws, size_t ws_size,
                              hipStream_t stream) {
    const float* X    = (const float*)d_in[0];
    const float* W_ih = (const float*)d_in[1];
    const float* b_ih = (const float*)d_in[2];
    const float* W_hh = (const float*)d_in[3];
    const float* b_hh = (const float*)d_in[4];
    const float* W_ho = (const float*)d_in[5];
    const float* b_ho = (const float*)d_in[6];
    float* out = (float*)d_out;

    rnn_persistent_kernel<<<dim3(BATCH / 2), dim3(256), 0, stream>>>(
        X, W_ih, b_ih, W_hh, b_hh, W_ho, b_ho, out);
}